// Round 1
// baseline (2077.418 us; speedup 1.0000x reference)
//
#include <hip/hip_runtime.h>
#include <math.h>

#define B_ 4
#define L_ 8192
#define D_ 1024
#define C_ 2048          // L_ / chunk_divisor(=4)
#define TM 64            // tokens per workgroup in GEMM kernel
#define BN 128           // output-column block
#define BK 32            // k block
#define NB (D_/BN)       // 8
#define NKB (D_/BK)      // 32
#define CG 128           // chunks per scan group
#define NG (C_/CG)       // 16

// ---------------------------------------------------------------------------
// Kernel 1: fused  Q = x[t]*Wq^T, K = x[t-1]*Wk^T, cos = <Qhat,Khat>, p[b,t]
// One WG per 64 tokens. LDS tiles: x (65 rows x 32 k), Wq/Wk (32 k x 128 e).
// Thread (trg,tc): rows 4*trg..+3, cols 8*tc..+7. K-shifted rows align so the
// per-thread fragment product directly accumulates dot(Q[t], K[t-1]).
// ---------------------------------------------------------------------------
__global__ __launch_bounds__(256) void k_cos_p(
    const float* __restrict__ x, const float* __restrict__ Wq,
    const float* __restrict__ Wk, float* __restrict__ p)
{
    __shared__ float xs[TM + 1][44];    // pad 44: aligned float4 writes, 2-way-max read conflicts
    __shared__ float wqs[BK][132];      // [k][e], pad 132
    __shared__ float wks[BK][132];

    const int tid = threadIdx.x;
    const int b  = blockIdx.y;
    const int t0 = blockIdx.x * TM;
    const int tc  = tid & 15;
    const int trg = tid >> 4;
    const int rr  = trg << 2;
    const int cc  = tc << 3;

    float nq[4], nk[4], dt[4];
#pragma unroll
    for (int i = 0; i < 4; ++i) { nq[i] = 0.f; nk[i] = 0.f; dt[i] = 0.f; }

    // staging assignments
    const int xr = tid >> 2;            // x row 0..63
    const int xc = (tid & 3) << 3;      // x col start (8 floats)
    int xrow = t0 - 1 + xr; if (xrow < 0) xrow = 0;
    const int we = tid >> 1;            // W row (output col) 0..127
    const int wh = tid & 1;             // which 16-col half

    for (int nb = 0; nb < NB; ++nb) {
        const int eb = nb * BN;
        float qa[4][8], ka[4][8];
#pragma unroll
        for (int i = 0; i < 4; ++i)
#pragma unroll
            for (int j = 0; j < 8; ++j) { qa[i][j] = 0.f; ka[i][j] = 0.f; }

        for (int kb = 0; kb < NKB; ++kb) {
            const int k0 = kb * BK;
            // ---- stage x tile (rows = tokens t0-1 .. t0+63) ----
            {
                const float* src = &x[((size_t)b * L_ + xrow) * D_ + k0 + xc];
                float4 v0 = *(const float4*)src;
                float4 v1 = *(const float4*)(src + 4);
                *(float4*)&xs[xr][xc]     = v0;
                *(float4*)&xs[xr][xc + 4] = v1;
                if (tid < 4) {
                    const float* s2 = &x[((size_t)b * L_ + (t0 + 63)) * D_ + k0 + (tid << 3)];
                    float4 u0 = *(const float4*)s2;
                    float4 u1 = *(const float4*)(s2 + 4);
                    *(float4*)&xs[64][tid << 3]       = u0;
                    *(float4*)&xs[64][(tid << 3) + 4] = u1;
                }
            }
            // ---- stage W tiles transposed to [k][e] ----
            {
                const float* gq = &Wq[(size_t)(eb + we) * D_ + k0 + wh * 16];
                float tq[16];
                *(float4*)&tq[0]  = ((const float4*)gq)[0];
                *(float4*)&tq[4]  = ((const float4*)gq)[1];
                *(float4*)&tq[8]  = ((const float4*)gq)[2];
                *(float4*)&tq[12] = ((const float4*)gq)[3];
#pragma unroll
                for (int c = 0; c < 16; ++c) wqs[wh * 16 + c][we] = tq[c];
                const float* gk = &Wk[(size_t)(eb + we) * D_ + k0 + wh * 16];
                float tk[16];
                *(float4*)&tk[0]  = ((const float4*)gk)[0];
                *(float4*)&tk[4]  = ((const float4*)gk)[1];
                *(float4*)&tk[8]  = ((const float4*)gk)[2];
                *(float4*)&tk[12] = ((const float4*)gk)[3];
#pragma unroll
                for (int c = 0; c < 16; ++c) wks[wh * 16 + c][we] = tk[c];
            }
            __syncthreads();
#pragma unroll 4
            for (int k = 0; k < BK; ++k) {
                float xv[5];
#pragma unroll
                for (int i = 0; i < 5; ++i) xv[i] = xs[rr + i][k];
                float wqv[8], wkv[8];
                *(float4*)&wqv[0] = *(const float4*)&wqs[k][cc];
                *(float4*)&wqv[4] = *(const float4*)&wqs[k][cc + 4];
                *(float4*)&wkv[0] = *(const float4*)&wks[k][cc];
                *(float4*)&wkv[4] = *(const float4*)&wks[k][cc + 4];
#pragma unroll
                for (int i = 0; i < 4; ++i)
#pragma unroll
                    for (int j = 0; j < 8; ++j) {
                        qa[i][j] = fmaf(xv[i + 1], wqv[j], qa[i][j]); // Q row = token t0+rr+i
                        ka[i][j] = fmaf(xv[i],     wkv[j], ka[i][j]); // K row = token t0+rr+i-1
                    }
            }
            __syncthreads();
        }
        // fold this column block into per-token partials
#pragma unroll
        for (int i = 0; i < 4; ++i) {
            float a0 = 0.f, a1 = 0.f, a2 = 0.f;
#pragma unroll
            for (int j = 0; j < 8; ++j) {
                a0 = fmaf(qa[i][j], qa[i][j], a0);
                a1 = fmaf(ka[i][j], ka[i][j], a1);
                a2 = fmaf(qa[i][j], ka[i][j], a2);
            }
            nq[i] += a0; nk[i] += a1; dt[i] += a2;
        }
    }
    // reduce across the 16 lanes sharing a row group (consecutive lanes)
#pragma unroll
    for (int m = 1; m < 16; m <<= 1) {
#pragma unroll
        for (int i = 0; i < 4; ++i) {
            nq[i] += __shfl_xor(nq[i], m);
            nk[i] += __shfl_xor(nk[i], m);
            dt[i] += __shfl_xor(dt[i], m);
        }
    }
    if (tc == 0) {
#pragma unroll
        for (int i = 0; i < 4; ++i) {
            int t = t0 + rr + i;
            float qn = fmaxf(sqrtf(nq[i]), 1e-12f);
            float kn = fmaxf(sqrtf(nk[i]), 1e-12f);
            float cs = dt[i] / (qn * kn);
            float pv = (1.0f - cs) * 0.5f;
            pv = fminf(fmaxf(pv, 0.0f), 1.0f);
            p[b * L_ + t] = (t == 0) ? 1.0f : pv;
        }
    }
}

// ---------------------------------------------------------------------------
// Kernel 2: per-batch boundary compaction. 1 WG (1024 thr) per batch.
// take[b][r] = position of r-th boundary token; nch[b] = min(#bounds, C).
// ---------------------------------------------------------------------------
__global__ __launch_bounds__(1024) void k_boundaries(
    const float* __restrict__ p, int* __restrict__ take, int* __restrict__ nch)
{
    const int b = blockIdx.x;
    const int tid = threadIdx.x;
    __shared__ int ssum[1024];

    bool m[8];
    int local = 0;
#pragma unroll
    for (int j = 0; j < 8; ++j) {
        int l = tid * 8 + j;
        m[j] = (p[b * L_ + l] >= 0.5f);
        local += m[j] ? 1 : 0;
    }
    ssum[tid] = local;
    __syncthreads();
    for (int off = 1; off < 1024; off <<= 1) {
        int add = (tid >= off) ? ssum[tid - off] : 0;
        __syncthreads();
        ssum[tid] += add;
        __syncthreads();
    }
    const int total = ssum[1023];
    int rank = ssum[tid] - local;   // exclusive prefix
#pragma unroll
    for (int j = 0; j < 8; ++j) {
        if (m[j]) {
            if (rank < C_) take[b * C_ + rank] = tid * 8 + j;
            ++rank;
        }
    }
    if (tid == 0) nch[b] = (total < C_) ? total : C_;
    for (int c = total + tid; c < C_; c += 1024) take[b * C_ + c] = 0;
}

// ---------------------------------------------------------------------------
// Kernel 3a: blocked chunk scan, local pass. Wave = 64 consecutive d lanes.
// Recurrence s[c] = w[c] + decay[c]*s[c-1], decay scalar per chunk.
// Stores group end-state E and group decay-product M.
// ---------------------------------------------------------------------------
__global__ __launch_bounds__(256) void k_scan_local(
    const float* __restrict__ x, const float* __restrict__ p,
    const int* __restrict__ take, float* __restrict__ E, float* __restrict__ M)
{
    const int g = blockIdx.x, b = blockIdx.y, zq = blockIdx.z;
    const int w = threadIdx.x >> 6, lane = threadIdx.x & 63;
    const int d = ((zq << 2) + w) * 64 + lane;

    float s = 0.f, mm = 1.f;
    const int c0 = g * CG;
    for (int c = c0; c < c0 + CG; ++c) {
        int idx = take[b * C_ + c];
        float pc = p[b * L_ + idx];
        pc = fminf(fmaxf(pc, 1e-4f), 1.f - 1e-4f);
        float dc = (c == 0) ? 0.f : (1.f - pc);
        float wc = (c == 0) ? 1.f : pc;
        float xv = x[((size_t)b * L_ + idx) * D_ + d];
        s = fmaf(dc, s, wc * xv);
        mm *= dc;
    }
    E[((size_t)b * NG + g) * D_ + d] = s;
    if (threadIdx.x == 0 && zq == 0) M[b * NG + g] = mm;
}

// ---------------------------------------------------------------------------
// Kernel 3b: cross-group scan (16 steps), writes carry-in per group.
// ---------------------------------------------------------------------------
__global__ __launch_bounds__(256) void k_scan_groups(
    const float* __restrict__ E, const float* __restrict__ M, float* __restrict__ carry)
{
    const int gid = blockIdx.x * 256 + threadIdx.x;   // 0..4095
    const int b = gid >> 10, d = gid & 1023;
    float s = 0.f;
    for (int g = 0; g < NG; ++g) {
        carry[((size_t)b * NG + g) * D_ + d] = s;
        s = E[((size_t)b * NG + g) * D_ + d] + M[b * NG + g] * s;
    }
}

// ---------------------------------------------------------------------------
// Kernel 3c: rescan with correct carry, broadcast each chunk's state to its
// token segment [take[c], take[c+1]) (last real chunk extends to L).
// ---------------------------------------------------------------------------
__global__ __launch_bounds__(256) void k_scan_out(
    const float* __restrict__ x, const float* __restrict__ p,
    const int* __restrict__ take, const int* __restrict__ nch,
    const float* __restrict__ carry, float* __restrict__ out)
{
    const int g = blockIdx.x, b = blockIdx.y, zq = blockIdx.z;
    const int w = threadIdx.x >> 6, lane = threadIdx.x & 63;
    const int d = ((zq << 2) + w) * 64 + lane;

    const int K = nch[b];
    float s = carry[((size_t)b * NG + g) * D_ + d];
    const int c0 = g * CG;
    const int c1 = (c0 + CG < K) ? (c0 + CG) : K;
    for (int c = c0; c < c1; ++c) {
        int idx = take[b * C_ + c];
        float pc = p[b * L_ + idx];
        pc = fminf(fmaxf(pc, 1e-4f), 1.f - 1e-4f);
        float dc = (c == 0) ? 0.f : (1.f - pc);
        float wc = (c == 0) ? 1.f : pc;
        float xv = x[((size_t)b * L_ + idx) * D_ + d];
        s = fmaf(dc, s, wc * xv);
        int segb = idx;
        int sege = (c + 1 < K) ? take[b * C_ + c + 1] : L_;
        for (int l = segb; l < sege; ++l)
            out[((size_t)b * L_ + l) * D_ + d] = s;
    }
}

// ---------------------------------------------------------------------------
extern "C" void kernel_launch(void* const* d_in, const int* in_sizes, int n_in,
                              void* d_out, int out_size, void* d_ws, size_t ws_size,
                              hipStream_t stream)
{
    (void)in_sizes; (void)n_in; (void)out_size;
    const float* x  = (const float*)d_in[0];
    const float* Wq = (const float*)d_in[1];
    const float* Wk = (const float*)d_in[2];
    float* out = (float*)d_out;

    char* ws = (char*)d_ws;
    float* p    = (float*)(ws + 0);            // 4*B*L      = 524288 B
    int*   take = (int*)  (ws + 524288);       // 4*B*C      =  32768 B
    int*   nch  = (int*)  (ws + 557056);       // 64 B
    float* M    = (float*)(ws + 557120);       // 256 B
    float* E    = (float*)(ws + 557376);       // 262144 B
    float* carry= (float*)(ws + 819520);       // 262144 B -> 1081664 total
    if (ws_size < 1081664u) return;

    dim3 g1(L_ / TM, B_);
    k_cos_p<<<g1, 256, 0, stream>>>(x, Wq, Wk, p);
    k_boundaries<<<B_, 1024, 0, stream>>>(p, take, nch);
    dim3 g3(NG, B_, D_ / 256);
    k_scan_local<<<g3, 256, 0, stream>>>(x, p, take, E, M);
    k_scan_groups<<<(B_ * D_) / 256, 256, 0, stream>>>(E, M, carry);
    k_scan_out<<<g3, 256, 0, stream>>>(x, p, take, nch, carry, out);
}

// Round 2
// 782.636 us; speedup vs baseline: 2.6544x; 2.6544x over previous
//
#include <hip/hip_runtime.h>
#include <math.h>

#define B_ 4
#define L_ 8192
#define D_ 1024
#define C_ 2048          // L_ / chunk_divisor(=4)
#define CG 128           // chunks per scan group
#define NG (C_/CG)       // 16
#define TAUF 7.5e-4f     // |cos| below this -> exact f32 fixup
#define MAXF 4096

using f32x4  = __attribute__((ext_vector_type(4))) float;
using bf16x8 = __attribute__((ext_vector_type(8))) short;

__device__ __forceinline__ unsigned short f2bf(float f) {
    unsigned int u = __float_as_uint(f);
    u = (u + 0x7fffu + ((u >> 16) & 1u)) >> 16;   // RNE
    return (unsigned short)u;
}

// ---------------------------------------------------------------------------
// k_prep: E = W - I, rounded to bf16 bits, row-major [e][k]
// ---------------------------------------------------------------------------
__global__ __launch_bounds__(256) void k_prep(
    const float* __restrict__ Wq, const float* __restrict__ Wk,
    unsigned short* __restrict__ eqb, unsigned short* __restrict__ ekb)
{
    const float* W = blockIdx.y ? Wk : Wq;
    unsigned short* E = blockIdx.y ? ekb : eqb;
    size_t i8 = ((size_t)blockIdx.x * 256 + threadIdx.x) * 8;
    int e = (int)(i8 >> 10), k0 = (int)(i8 & 1023);
    float4 a = *(const float4*)&W[i8];
    float4 b = *(const float4*)&W[i8 + 4];
    float v[8] = {a.x, a.y, a.z, a.w, b.x, b.y, b.z, b.w};
    unsigned short o[8];
#pragma unroll
    for (int j = 0; j < 8; ++j) {
        float t = v[j] - ((k0 + j == e) ? 1.0f : 0.0f);
        o[j] = f2bf(t);
    }
    *(uint4*)&E[i8] = *(uint4*)o;
}

// ---------------------------------------------------------------------------
// k_gemm: U = x_bf16 * [Eq^T | Ek^T] via 16x16x32 bf16 MFMA, fused epilogue:
// q = x_t + u_t, k = x_{t-1} + v_{t-1}; accumulate nq, nk, dt per token; p.
// Grid (64, B): WG = 512 thr = 8 waves; token tile 128 (+1 shifted row).
// Wave w: rows (w&3)*32..+31, e-cols (w>>2)*64..+63 of the 128-col nb block.
// LDS rows are 128B, XOR-swizzled (byte ^= (row&7)<<4) for conflict-free
// ds_read_b128 (G4).
// ---------------------------------------------------------------------------
__global__ __launch_bounds__(512) void k_gemm(
    const float* __restrict__ x, const unsigned short* __restrict__ eqb,
    const unsigned short* __restrict__ ekb, float* __restrict__ p,
    int* __restrict__ cnt, int* __restrict__ flags)
{
    __shared__ unsigned short xs[129 * 64];
    __shared__ unsigned short eqs[128 * 64];
    __shared__ unsigned short eks[128 * 64];
    __shared__ float part[128][4];

    const int tid = threadIdx.x;
    const int b = blockIdx.y;
    const int t0 = blockIdx.x * 128;
    const int lane = tid & 63;
    const int w = tid >> 6;
    const int wr = w & 3, wc = w >> 2;
    const int l15 = lane & 15, lg = lane >> 4;

    float nq[8], nk[8], dt[8];
#pragma unroll
    for (int i = 0; i < 8; ++i) { nq[i] = 0.f; nk[i] = 0.f; dt[i] = 0.f; }

    // staging assignments
    const int srow = tid >> 2;          // x row 0..127
    const int sq   = tid & 3;           // 16-f32 quarter
    int stok = t0 - 1 + srow; if (stok < 0) stok = 0;
    const int erow  = (tid & 255) >> 1; // E row 0..127
    const int ehalf = tid & 1;
    unsigned short* emat = (tid < 256) ? eqs : eks;
    const unsigned short* egl = (tid < 256) ? eqb : ekb;

    for (int nb = 0; nb < 8; ++nb) {
        const int e0 = nb * 128;
        f32x4 acc[2][8];
#pragma unroll
        for (int rb = 0; rb < 2; ++rb)
#pragma unroll
            for (int f = 0; f < 8; ++f) acc[rb][f] = (f32x4){0.f, 0.f, 0.f, 0.f};

        for (int kb = 0; kb < 16; ++kb) {
            const int k0 = kb * 64;
            // ---- stage x tile rows (tokens t0-1 .. t0+127), f32 -> bf16 ----
            {
                const float* src = &x[((size_t)b * L_ + stok) * D_ + k0 + sq * 16];
                float4 v0 = ((const float4*)src)[0];
                float4 v1 = ((const float4*)src)[1];
                float4 v2 = ((const float4*)src)[2];
                float4 v3 = ((const float4*)src)[3];
                unsigned short t8a[8] = {f2bf(v0.x), f2bf(v0.y), f2bf(v0.z), f2bf(v0.w),
                                         f2bf(v1.x), f2bf(v1.y), f2bf(v1.z), f2bf(v1.w)};
                unsigned short t8b[8] = {f2bf(v2.x), f2bf(v2.y), f2bf(v2.z), f2bf(v2.w),
                                         f2bf(v3.x), f2bf(v3.y), f2bf(v3.z), f2bf(v3.w)};
                const int c0 = sq * 16, sw = (srow & 7) << 3;
                *(uint4*)&xs[srow * 64 + ((c0    ) ^ sw)] = *(uint4*)t8a;
                *(uint4*)&xs[srow * 64 + ((c0 + 8) ^ sw)] = *(uint4*)t8b;
                if (tid < 4) {  // row 128 (token t0+127), swizzle bits = 0
                    const float* s2 = &x[((size_t)b * L_ + (t0 + 127)) * D_ + k0 + tid * 16];
                    float4 u0 = ((const float4*)s2)[0];
                    float4 u1 = ((const float4*)s2)[1];
                    float4 u2 = ((const float4*)s2)[2];
                    float4 u3 = ((const float4*)s2)[3];
                    unsigned short u8a[8] = {f2bf(u0.x), f2bf(u0.y), f2bf(u0.z), f2bf(u0.w),
                                             f2bf(u1.x), f2bf(u1.y), f2bf(u1.z), f2bf(u1.w)};
                    unsigned short u8b[8] = {f2bf(u2.x), f2bf(u2.y), f2bf(u2.z), f2bf(u2.w),
                                             f2bf(u3.x), f2bf(u3.y), f2bf(u3.z), f2bf(u3.w)};
                    *(uint4*)&xs[128 * 64 + tid * 16    ] = *(uint4*)u8a;
                    *(uint4*)&xs[128 * 64 + tid * 16 + 8] = *(uint4*)u8b;
                }
            }
            // ---- stage Eq/Ek tiles (bf16, already global) ----
            {
                const unsigned short* src = &egl[(size_t)(e0 + erow) * D_ + k0 + ehalf * 32];
                uint4 u0 = ((const uint4*)src)[0];
                uint4 u1 = ((const uint4*)src)[1];
                uint4 u2 = ((const uint4*)src)[2];
                uint4 u3 = ((const uint4*)src)[3];
                const int c0 = ehalf * 32, sw = (erow & 7) << 3;
                *(uint4*)&emat[erow * 64 + ((c0     ) ^ sw)] = u0;
                *(uint4*)&emat[erow * 64 + ((c0 +  8) ^ sw)] = u1;
                *(uint4*)&emat[erow * 64 + ((c0 + 16) ^ sw)] = u2;
                *(uint4*)&emat[erow * 64 + ((c0 + 24) ^ sw)] = u3;
            }
            __syncthreads();
#pragma unroll
            for (int ks = 0; ks < 2; ++ks) {
                const int kk = ks * 32 + lg * 8;
                bf16x8 aq[2], ak[2], bq[4], bk[4];
#pragma unroll
                for (int rb = 0; rb < 2; ++rb) {
                    int rq = 1 + wr * 32 + rb * 16 + l15;   // token t0 + rq-1
                    int rk = rq - 1;
                    aq[rb] = *(const bf16x8*)&xs[rq * 64 + (kk ^ ((rq & 7) << 3))];
                    ak[rb] = *(const bf16x8*)&xs[rk * 64 + (kk ^ ((rk & 7) << 3))];
                }
#pragma unroll
                for (int cf = 0; cf < 4; ++cf) {
                    int er = wc * 64 + cf * 16 + l15;
                    int off = er * 64 + (kk ^ ((er & 7) << 3));
                    bq[cf] = *(const bf16x8*)&eqs[off];
                    bk[cf] = *(const bf16x8*)&eks[off];
                }
#pragma unroll
                for (int rb = 0; rb < 2; ++rb)
#pragma unroll
                    for (int cf = 0; cf < 4; ++cf) {
                        acc[rb][cf]     = __builtin_amdgcn_mfma_f32_16x16x32_bf16(aq[rb], bq[cf], acc[rb][cf],     0, 0, 0);
                        acc[rb][cf + 4] = __builtin_amdgcn_mfma_f32_16x16x32_bf16(ak[rb], bk[cf], acc[rb][cf + 4], 0, 0, 0);
                    }
            }
            __syncthreads();
        }
        // ---- epilogue fold for this nb block: q = x + u, k = x' + v ----
#pragma unroll
        for (int rb = 0; rb < 2; ++rb)
#pragma unroll
            for (int cf = 0; cf < 4; ++cf) {
                const int ecol = e0 + wc * 64 + cf * 16 + l15;
#pragma unroll
                for (int r = 0; r < 4; ++r) {
                    const int rl = wr * 32 + rb * 16 + lg * 4 + r;
                    const int t = t0 + rl;
                    const int tm = (t > 0) ? t - 1 : 0;
                    float xt = x[((size_t)b * L_ + t) * D_ + ecol];
                    float xm = x[((size_t)b * L_ + tm) * D_ + ecol];
                    float qe = xt + acc[rb][cf][r];
                    float ke = xm + acc[rb][cf + 4][r];
                    const int s = rb * 4 + r;
                    nq[s] = fmaf(qe, qe, nq[s]);
                    nk[s] = fmaf(ke, ke, nk[s]);
                    dt[s] = fmaf(qe, ke, dt[s]);
                }
            }
    }
    // reduce across the 16 col-lanes
#pragma unroll
    for (int m = 1; m < 16; m <<= 1) {
#pragma unroll
        for (int s = 0; s < 8; ++s) {
            nq[s] += __shfl_xor(nq[s], m);
            nk[s] += __shfl_xor(nk[s], m);
            dt[s] += __shfl_xor(dt[s], m);
        }
    }
    if (wc == 1 && l15 == 0) {
#pragma unroll
        for (int s = 0; s < 8; ++s) {
            int rl = wr * 32 + (s >> 2) * 16 + lg * 4 + (s & 3);
            part[rl][0] = nq[s]; part[rl][1] = nk[s]; part[rl][2] = dt[s];
        }
    }
    __syncthreads();
    if (wc == 0 && l15 == 0) {
#pragma unroll
        for (int s = 0; s < 8; ++s) {
            int rl = wr * 32 + (s >> 2) * 16 + lg * 4 + (s & 3);
            int t = t0 + rl;
            float a = nq[s] + part[rl][0];
            float c = nk[s] + part[rl][1];
            float d = dt[s] + part[rl][2];
            float qn = fmaxf(sqrtf(a), 1e-12f);
            float kn = fmaxf(sqrtf(c), 1e-12f);
            float cs = d / (qn * kn);
            float pv = fminf(fmaxf((1.0f - cs) * 0.5f, 0.0f), 1.0f);
            if (t == 0) pv = 1.0f;
            p[b * L_ + t] = pv;
            if (t > 0 && fabsf(cs) < TAUF) {
                int idx = atomicAdd(cnt, 1);
                if (idx < MAXF) flags[idx] = b * L_ + t;
            }
        }
    }
}

// ---------------------------------------------------------------------------
// k_fix: exact f32 recompute for flagged tokens. Gathered tall-skinny GEMM:
// 64 flags x 128 e-cols per WG, K=1024. Writes partial (nq,nk,dt) per e-block.
// ---------------------------------------------------------------------------
__global__ __launch_bounds__(256) void k_fix(
    const float* __restrict__ x, const float* __restrict__ Wq,
    const float* __restrict__ Wk, const int* __restrict__ cnt,
    const int* __restrict__ flags, float* __restrict__ parts)
{
    int n = *cnt; if (n > MAXF) n = MAXF;
    const int m0 = blockIdx.x * 64;
    if (m0 >= n) return;
    const int eb = blockIdx.y * 128;

    __shared__ float Ats[64][36];
    __shared__ float Atm[64][36];
    __shared__ float wqs[32][132];
    __shared__ float wks[32][132];

    const int tid = threadIdx.x;
    const int tc = tid & 15, trg = tid >> 4;
    const int rr = trg << 2, cc = tc << 3;

    const int arow = tid >> 2;   // staging flag-row 0..63
    const int aq4  = tid & 3;
    int gsl = m0 + arow;
    int gf = (gsl < n) ? flags[gsl] : flags[m0];
    const int fb = gf >> 13, ft = gf & (L_ - 1);   // ft >= 1 always
    const int we = tid >> 1;     // W row 0..127
    const int wh = tid & 1;

    float qa[4][8], ka[4][8];
#pragma unroll
    for (int i = 0; i < 4; ++i)
#pragma unroll
        for (int j = 0; j < 8; ++j) { qa[i][j] = 0.f; ka[i][j] = 0.f; }

    for (int kb = 0; kb < 32; ++kb) {
        const int k0 = kb * 32;
        {
            const float* s1 = &x[((size_t)fb * L_ + ft) * D_ + k0 + aq4 * 8];
            *(float4*)&Ats[arow][aq4 * 8]     = ((const float4*)s1)[0];
            *(float4*)&Ats[arow][aq4 * 8 + 4] = ((const float4*)s1)[1];
            const float* s2 = &x[((size_t)fb * L_ + (ft - 1)) * D_ + k0 + aq4 * 8];
            *(float4*)&Atm[arow][aq4 * 8]     = ((const float4*)s2)[0];
            *(float4*)&Atm[arow][aq4 * 8 + 4] = ((const float4*)s2)[1];
        }
        {
            const float* gq = &Wq[(size_t)(eb + we) * D_ + k0 + wh * 16];
            float tq[16];
            *(float4*)&tq[0]  = ((const float4*)gq)[0];
            *(float4*)&tq[4]  = ((const float4*)gq)[1];
            *(float4*)&tq[8]  = ((const float4*)gq)[2];
            *(float4*)&tq[12] = ((const float4*)gq)[3];
#pragma unroll
            for (int c = 0; c < 16; ++c) wqs[wh * 16 + c][we] = tq[c];
            const float* gk = &Wk[(size_t)(eb + we) * D_ + k0 + wh * 16];
            float tk[16];
            *(float4*)&tk[0]  = ((const float4*)gk)[0];
            *(float4*)&tk[4]  = ((const float4*)gk)[1];
            *(float4*)&tk[8]  = ((const float4*)gk)[2];
            *(float4*)&tk[12] = ((const float4*)gk)[3];
#pragma unroll
            for (int c = 0; c < 16; ++c) wks[wh * 16 + c][we] = tk[c];
        }
        __syncthreads();
#pragma unroll 4
        for (int k = 0; k < 32; ++k) {
            float xt[4], xm[4];
#pragma unroll
            for (int i = 0; i < 4; ++i) { xt[i] = Ats[rr + i][k]; xm[i] = Atm[rr + i][k]; }
            float wqv[8], wkv[8];
            *(float4*)&wqv[0] = *(const float4*)&wqs[k][cc];
            *(float4*)&wqv[4] = *(const float4*)&wqs[k][cc + 4];
            *(float4*)&wkv[0] = *(const float4*)&wks[k][cc];
            *(float4*)&wkv[4] = *(const float4*)&wks[k][cc + 4];
#pragma unroll
            for (int i = 0; i < 4; ++i)
#pragma unroll
                for (int j = 0; j < 8; ++j) {
                    qa[i][j] = fmaf(xt[i], wqv[j], qa[i][j]);
                    ka[i][j] = fmaf(xm[i], wkv[j], ka[i][j]);
                }
        }
        __syncthreads();
    }
#pragma unroll
    for (int i = 0; i < 4; ++i) {
        float a0 = 0.f, a1 = 0.f, a2 = 0.f;
#pragma unroll
        for (int j = 0; j < 8; ++j) {
            a0 = fmaf(qa[i][j], qa[i][j], a0);
            a1 = fmaf(ka[i][j], ka[i][j], a1);
            a2 = fmaf(qa[i][j], ka[i][j], a2);
        }
#pragma unroll
        for (int m = 1; m < 16; m <<= 1) {
            a0 += __shfl_xor(a0, m);
            a1 += __shfl_xor(a1, m);
            a2 += __shfl_xor(a2, m);
        }
        if (tc == 0 && (m0 + rr + i) < n) {
            size_t o = ((size_t)(m0 + rr + i) * 8 + blockIdx.y) * 3;
            parts[o + 0] = a0; parts[o + 1] = a1; parts[o + 2] = a2;
        }
    }
}

__global__ __launch_bounds__(256) void k_fix_final(
    const int* __restrict__ cnt, const int* __restrict__ flags,
    const float* __restrict__ parts, float* __restrict__ p)
{
    int n = *cnt; if (n > MAXF) n = MAXF;
    int f = blockIdx.x * 256 + threadIdx.x;
    if (f >= n) return;
    float a = 0.f, c = 0.f, d = 0.f;
#pragma unroll
    for (int e = 0; e < 8; ++e) {
        size_t o = ((size_t)f * 8 + e) * 3;
        a += parts[o + 0]; c += parts[o + 1]; d += parts[o + 2];
    }
    float qn = fmaxf(sqrtf(a), 1e-12f);
    float kn = fmaxf(sqrtf(c), 1e-12f);
    float cs = d / (qn * kn);
    float pv = fminf(fmaxf((1.0f - cs) * 0.5f, 0.0f), 1.0f);
    p[flags[f]] = pv;
}

// ---------------------------------------------------------------------------
// k_boundaries: per-batch boundary compaction (unchanged).
// ---------------------------------------------------------------------------
__global__ __launch_bounds__(1024) void k_boundaries(
    const float* __restrict__ p, int* __restrict__ take, int* __restrict__ nch)
{
    const int b = blockIdx.x;
    const int tid = threadIdx.x;
    __shared__ int ssum[1024];

    bool m[8];
    int local = 0;
#pragma unroll
    for (int j = 0; j < 8; ++j) {
        int l = tid * 8 + j;
        m[j] = (p[b * L_ + l] >= 0.5f);
        local += m[j] ? 1 : 0;
    }
    ssum[tid] = local;
    __syncthreads();
    for (int off = 1; off < 1024; off <<= 1) {
        int add = (tid >= off) ? ssum[tid - off] : 0;
        __syncthreads();
        ssum[tid] += add;
        __syncthreads();
    }
    const int total = ssum[1023];
    int rank = ssum[tid] - local;
#pragma unroll
    for (int j = 0; j < 8; ++j) {
        if (m[j]) {
            if (rank < C_) take[b * C_ + rank] = tid * 8 + j;
            ++rank;
        }
    }
    if (tid == 0) nch[b] = (total < C_) ? total : C_;
    for (int c = total + tid; c < C_; c += 1024) take[b * C_ + c] = 0;
}

// ---------------------------------------------------------------------------
// Scan kernels (unchanged from round 1)
// ---------------------------------------------------------------------------
__global__ __launch_bounds__(256) void k_scan_local(
    const float* __restrict__ x, const float* __restrict__ p,
    const int* __restrict__ take, float* __restrict__ E, float* __restrict__ M)
{
    const int g = blockIdx.x, b = blockIdx.y, zq = blockIdx.z;
    const int w = threadIdx.x >> 6, lane = threadIdx.x & 63;
    const int d = ((zq << 2) + w) * 64 + lane;

    float s = 0.f, mm = 1.f;
    const int c0 = g * CG;
    for (int c = c0; c < c0 + CG; ++c) {
        int idx = take[b * C_ + c];
        float pc = p[b * L_ + idx];
        pc = fminf(fmaxf(pc, 1e-4f), 1.f - 1e-4f);
        float dc = (c == 0) ? 0.f : (1.f - pc);
        float wc = (c == 0) ? 1.f : pc;
        float xv = x[((size_t)b * L_ + idx) * D_ + d];
        s = fmaf(dc, s, wc * xv);
        mm *= dc;
    }
    E[((size_t)b * NG + g) * D_ + d] = s;
    if (threadIdx.x == 0 && zq == 0) M[b * NG + g] = mm;
}

__global__ __launch_bounds__(256) void k_scan_groups(
    const float* __restrict__ E, const float* __restrict__ M, float* __restrict__ carry)
{
    const int gid = blockIdx.x * 256 + threadIdx.x;
    const int b = gid >> 10, d = gid & 1023;
    float s = 0.f;
    for (int g = 0; g < NG; ++g) {
        carry[((size_t)b * NG + g) * D_ + d] = s;
        s = E[((size_t)b * NG + g) * D_ + d] + M[b * NG + g] * s;
    }
}

__global__ __launch_bounds__(256) void k_scan_out(
    const float* __restrict__ x, const float* __restrict__ p,
    const int* __restrict__ take, const int* __restrict__ nch,
    const float* __restrict__ carry, float* __restrict__ out)
{
    const int g = blockIdx.x, b = blockIdx.y, zq = blockIdx.z;
    const int w = threadIdx.x >> 6, lane = threadIdx.x & 63;
    const int d = ((zq << 2) + w) * 64 + lane;

    const int K = nch[b];
    float s = carry[((size_t)b * NG + g) * D_ + d];
    const int c0 = g * CG;
    const int c1 = (c0 + CG < K) ? (c0 + CG) : K;
    for (int c = c0; c < c1; ++c) {
        int idx = take[b * C_ + c];
        float pc = p[b * L_ + idx];
        pc = fminf(fmaxf(pc, 1e-4f), 1.f - 1e-4f);
        float dc = (c == 0) ? 0.f : (1.f - pc);
        float wc = (c == 0) ? 1.f : pc;
        float xv = x[((size_t)b * L_ + idx) * D_ + d];
        s = fmaf(dc, s, wc * xv);
        int segb = idx;
        int sege = (c + 1 < K) ? take[b * C_ + c + 1] : L_;
        for (int l = segb; l < sege; ++l)
            out[((size_t)b * L_ + l) * D_ + d] = s;
    }
}

// ---------------------------------------------------------------------------
extern "C" void kernel_launch(void* const* d_in, const int* in_sizes, int n_in,
                              void* d_out, int out_size, void* d_ws, size_t ws_size,
                              hipStream_t stream)
{
    (void)in_sizes; (void)n_in; (void)out_size;
    const float* x  = (const float*)d_in[0];
    const float* Wq = (const float*)d_in[1];
    const float* Wk = (const float*)d_in[2];
    float* out = (float*)d_out;

    char* ws = (char*)d_ws;
    float* p     = (float*)(ws + 0);              //   524288
    int*   take  = (int*)  (ws + 524288);         //    32768
    int*   nch   = (int*)  (ws + 557056);         //       64
    float* M     = (float*)(ws + 557120);         //      256
    float* E     = (float*)(ws + 557376);         //   262144
    float* carry = (float*)(ws + 819520);         //   262144
    unsigned short* eqb = (unsigned short*)(ws + 1081664);   // 2097152
    unsigned short* ekb = (unsigned short*)(ws + 3178816);   // 2097152
    int*   cnt   = (int*)  (ws + 5275968);        //       64
    int*   flags = (int*)  (ws + 5276032);        //    16384
    float* parts = (float*)(ws + 5292416);        //   393216 -> 5685632
    if (ws_size < 5685632u) return;

    hipMemsetAsync(cnt, 0, 64, stream);
    k_prep<<<dim3(512, 2), 256, 0, stream>>>(Wq, Wk, eqb, ekb);
    k_gemm<<<dim3(64, B_), 512, 0, stream>>>(x, eqb, ekb, p, cnt, flags);
    k_fix<<<dim3(MAXF / 64, 8), 256, 0, stream>>>(x, Wq, Wk, cnt, flags, parts);
    k_fix_final<<<MAXF / 256, 256, 0, stream>>>(cnt, flags, parts, p);
    k_boundaries<<<B_, 1024, 0, stream>>>(p, take, nch);
    dim3 g3(NG, B_, D_ / 256);
    k_scan_local<<<g3, 256, 0, stream>>>(x, p, take, E, M);
    k_scan_groups<<<(B_ * D_) / 256, 256, 0, stream>>>(E, M, carry);
    k_scan_out<<<g3, 256, 0, stream>>>(x, p, take, nch, carry, out);
}

// Round 3
// 581.395 us; speedup vs baseline: 3.5732x; 1.3461x over previous
//
#include <hip/hip_runtime.h>
#include <math.h>

#define B_ 4
#define L_ 8192
#define D_ 1024
#define C_ 2048          // L_ / chunk_divisor(=4)
#define CG 128           // chunks per scan group
#define NG (C_/CG)       // 16
#define TAUF 7.5e-4f     // |cos| below this -> exact f32 fixup
#define MAXF 4096

typedef unsigned short ushortt;
using f32x4  = __attribute__((ext_vector_type(4))) float;
using bf16x8 = __attribute__((ext_vector_type(8))) short;

__device__ __forceinline__ ushortt f2bf(float f) {
    unsigned int u = __float_as_uint(f);
    u = (u + 0x7fffu + ((u >> 16) & 1u)) >> 16;   // RNE
    return (ushortt)u;
}
__device__ __forceinline__ float bf2f(ushortt h) {
    unsigned int u = ((unsigned int)h) << 16;
    return __uint_as_float(u);
}

#define GLOAD16(gsrc, ldst) \
    __builtin_amdgcn_global_load_lds( \
        (const __attribute__((address_space(1))) unsigned int*)(gsrc), \
        (__attribute__((address_space(3))) unsigned int*)(ldst), 16, 0, 0)

// ---------------------------------------------------------------------------
// k_prep: E = W - I, rounded to bf16, row-major [e][k]
// ---------------------------------------------------------------------------
__global__ __launch_bounds__(256) void k_prep(
    const float* __restrict__ Wq, const float* __restrict__ Wk,
    ushortt* __restrict__ eqb, ushortt* __restrict__ ekb)
{
    const float* W = blockIdx.y ? Wk : Wq;
    ushortt* E = blockIdx.y ? ekb : eqb;
    size_t i8 = ((size_t)blockIdx.x * 256 + threadIdx.x) * 8;
    int e = (int)(i8 >> 10), k0 = (int)(i8 & 1023);
    float4 a = *(const float4*)&W[i8];
    float4 b = *(const float4*)&W[i8 + 4];
    float v[8] = {a.x, a.y, a.z, a.w, b.x, b.y, b.z, b.w};
    ushortt o[8];
#pragma unroll
    for (int j = 0; j < 8; ++j) {
        float t = v[j] - ((k0 + j == e) ? 1.0f : 0.0f);
        o[j] = f2bf(t);
    }
    *(uint4*)&E[i8] = *(uint4*)o;
}

// ---------------------------------------------------------------------------
// k_xb: x (f32) -> xb (bf16), done once (lives in first half of d_out)
// ---------------------------------------------------------------------------
__global__ __launch_bounds__(256) void k_xb(
    const float* __restrict__ x, ushortt* __restrict__ xb)
{
    size_t i8 = ((size_t)blockIdx.x * 256 + threadIdx.x) * 8;
    float4 a = *(const float4*)&x[i8];
    float4 b = *(const float4*)&x[i8 + 4];
    float v[8] = {a.x, a.y, a.z, a.w, b.x, b.y, b.z, b.w};
    ushortt o[8];
#pragma unroll
    for (int j = 0; j < 8; ++j) o[j] = f2bf(v[j]);
    *(uint4*)&xb[i8] = *(uint4*)o;
}

// ---------------------------------------------------------------------------
// k_gemm: U = xb * [Eq^T | Ek^T] via 16x16x32 bf16 MFMA; fused epilogue
// computes p. Double-buffered LDS, global_load_lds staging (linear dest,
// inverse-XOR-swizzled global source; reads apply the same XOR).
// Grid (64, B), 512 thr = 8 waves (wr=w&3: 32-token group, wc=w>>2: 64-ecol).
// ---------------------------------------------------------------------------
__global__ __launch_bounds__(512) void k_gemm(
    const ushortt* __restrict__ xb, const ushortt* __restrict__ eqb,
    const ushortt* __restrict__ ekb, const float* __restrict__ x,
    float* __restrict__ p, int* __restrict__ cnt, int* __restrict__ flags)
{
    __shared__ ushortt xsh[2][129 * 64];
    __shared__ ushortt eqsh[2][128 * 64];
    __shared__ ushortt eksh[2][128 * 64];
    __shared__ float part[128][4];

    const int tid = threadIdx.x;
    const int b = blockIdx.y;
    const int t0 = blockIdx.x * 128;
    const int lane = tid & 63;
    const int w = tid >> 6;
    const int wr = w & 3, wc = w >> 2;
    const int l15 = lane & 15, lg = lane >> 4;

    const int tq = tid & 255;
    const ushortt* egl = (tid < 256) ? eqb : ekb;

    float nq[8], nk[8], dt[8];
#pragma unroll
    for (int i = 0; i < 8; ++i) { nq[i] = 0.f; nk[i] = 0.f; dt[i] = 0.f; }

    f32x4 acc[2][8];
#pragma unroll
    for (int rb = 0; rb < 2; ++rb)
#pragma unroll
        for (int f = 0; f < 8; ++f) acc[rb][f] = (f32x4){0.f, 0.f, 0.f, 0.f};

    // ---- stage(it, buf): issue global_load_lds for iteration it ----
    auto stage = [&](int it, int buf) {
        const int kb = it & 15, nb = it >> 4;
        const int k0 = kb * 64, e0 = nb * 128;
        // extra x row 128 (token t0+127): reg round-trip by 8 threads
        uint4 extra;
        if (tid < 8)
            extra = *(const uint4*)&xb[((size_t)b * L_ + (t0 + 127)) * D_ + k0 + tid * 8];
        // x rows 0..127 (tokens t0-1 .. t0+126), 2 rounds
#pragma unroll
        for (int r = 0; r < 2; ++r) {
            int row = r * 64 + (tid >> 3), kg = tid & 7;
            int trow = t0 - 1 + row; if (trow < 0) trow = 0;
            const ushortt* src = &xb[((size_t)b * L_ + trow) * D_ + k0 + ((kg ^ (row & 7)) << 3)];
            GLOAD16(src, &xsh[buf][r * 4096 + tid * 8]);
        }
        // E tiles: waves 0..3 -> eq, waves 4..7 -> ek; 4 rounds each
        ushortt* edst = (tid < 256) ? eqsh[buf] : eksh[buf];
#pragma unroll
        for (int r = 0; r < 4; ++r) {
            int row = r * 32 + (tq >> 3), kg = tq & 7;
            const ushortt* src = &egl[(size_t)(e0 + row) * D_ + k0 + ((kg ^ (row & 7)) << 3)];
            GLOAD16(src, &edst[r * 2048 + tq * 8]);
        }
        if (tid < 8)
            *(uint4*)&xsh[buf][128 * 64 + tid * 8] = extra;
    };

    stage(0, 0);
    __syncthreads();

    int buf = 0;
    for (int it = 0; it < 128; ++it) {
        if (it + 1 < 128) stage(it + 1, buf ^ 1);
        // ---- compute on buf ----
        const ushortt* xsb = xsh[buf];
        const ushortt* eqs = eqsh[buf];
        const ushortt* eks = eksh[buf];
#pragma unroll
        for (int ks = 0; ks < 2; ++ks) {
            const int kk = ks * 32 + lg * 8;
            bf16x8 aq[2], ak[2], bq[4], bk[4];
#pragma unroll
            for (int rb = 0; rb < 2; ++rb) {
                int rq = 1 + wr * 32 + rb * 16 + l15;
                int rk = rq - 1;
                aq[rb] = *(const bf16x8*)&xsb[rq * 64 + (kk ^ ((rq & 7) << 3))];
                ak[rb] = *(const bf16x8*)&xsb[rk * 64 + (kk ^ ((rk & 7) << 3))];
            }
#pragma unroll
            for (int cf = 0; cf < 4; ++cf) {
                int er = wc * 64 + cf * 16 + l15;
                int off = er * 64 + (kk ^ ((er & 7) << 3));
                bq[cf] = *(const bf16x8*)&eqs[off];
                bk[cf] = *(const bf16x8*)&eks[off];
            }
#pragma unroll
            for (int rb = 0; rb < 2; ++rb)
#pragma unroll
                for (int cf = 0; cf < 4; ++cf) {
                    acc[rb][cf]     = __builtin_amdgcn_mfma_f32_16x16x32_bf16(aq[rb], bq[cf], acc[rb][cf],     0, 0, 0);
                    acc[rb][cf + 4] = __builtin_amdgcn_mfma_f32_16x16x32_bf16(ak[rb], bk[cf], acc[rb][cf + 4], 0, 0, 0);
                }
        }
        // ---- fold at nb boundary ----
        if ((it & 15) == 15) {
            const int e0 = (it >> 4) * 128;
#pragma unroll
            for (int rb = 0; rb < 2; ++rb)
#pragma unroll
                for (int cf = 0; cf < 4; ++cf) {
                    const int ecol = e0 + wc * 64 + cf * 16 + l15;
                    const int tb = t0 + wr * 32 + rb * 16 + lg * 4;
                    const float* xc = &x[((size_t)b * L_ + tb) * D_ + ecol];
                    float xt0 = xc[0], xt1 = xc[D_], xt2 = xc[2 * D_], xt3 = xc[3 * D_];
                    float xm0 = (tb == 0) ? xt0 : xc[-(int)D_];
                    float xtv[4] = {xt0, xt1, xt2, xt3};
                    float xmv[4] = {xm0, xt0, xt1, xt2};
#pragma unroll
                    for (int r = 0; r < 4; ++r) {
                        float qe = xtv[r] + acc[rb][cf][r];
                        float ke = xmv[r] + acc[rb][cf + 4][r];
                        const int s = rb * 4 + r;
                        nq[s] = fmaf(qe, qe, nq[s]);
                        nk[s] = fmaf(ke, ke, nk[s]);
                        dt[s] = fmaf(qe, ke, dt[s]);
                    }
                }
#pragma unroll
            for (int rb = 0; rb < 2; ++rb)
#pragma unroll
                for (int f = 0; f < 8; ++f) acc[rb][f] = (f32x4){0.f, 0.f, 0.f, 0.f};
        }
        __syncthreads();
        buf ^= 1;
    }

    // reduce across the 16 col-lanes
#pragma unroll
    for (int m = 1; m < 16; m <<= 1) {
#pragma unroll
        for (int s = 0; s < 8; ++s) {
            nq[s] += __shfl_xor(nq[s], m);
            nk[s] += __shfl_xor(nk[s], m);
            dt[s] += __shfl_xor(dt[s], m);
        }
    }
    if (wc == 1 && l15 == 0) {
#pragma unroll
        for (int s = 0; s < 8; ++s) {
            int rl = wr * 32 + (s >> 2) * 16 + lg * 4 + (s & 3);
            part[rl][0] = nq[s]; part[rl][1] = nk[s]; part[rl][2] = dt[s];
        }
    }
    __syncthreads();
    if (wc == 0 && l15 == 0) {
#pragma unroll
        for (int s = 0; s < 8; ++s) {
            int rl = wr * 32 + (s >> 2) * 16 + lg * 4 + (s & 3);
            int t = t0 + rl;
            float a = nq[s] + part[rl][0];
            float c = nk[s] + part[rl][1];
            float d = dt[s] + part[rl][2];
            float qn = fmaxf(sqrtf(a), 1e-12f);
            float kn = fmaxf(sqrtf(c), 1e-12f);
            float cs = d / (qn * kn);
            float pv = fminf(fmaxf((1.0f - cs) * 0.5f, 0.0f), 1.0f);
            if (t == 0) pv = 1.0f;
            p[b * L_ + t] = pv;
            if (t > 0 && fabsf(cs) < TAUF) {
                int idx = atomicAdd(cnt, 1);
                if (idx < MAXF) flags[idx] = b * L_ + t;
            }
        }
    }
}

// ---------------------------------------------------------------------------
// k_fix: exact f32 recompute for flagged tokens (unchanged from round 2)
// ---------------------------------------------------------------------------
__global__ __launch_bounds__(256) void k_fix(
    const float* __restrict__ x, const float* __restrict__ Wq,
    const float* __restrict__ Wk, const int* __restrict__ cnt,
    const int* __restrict__ flags, float* __restrict__ parts)
{
    int n = *cnt; if (n > MAXF) n = MAXF;
    const int m0 = blockIdx.x * 64;
    if (m0 >= n) return;
    const int eb = blockIdx.y * 128;

    __shared__ float Ats[64][36];
    __shared__ float Atm[64][36];
    __shared__ float wqs[32][132];
    __shared__ float wks[32][132];

    const int tid = threadIdx.x;
    const int tc = tid & 15, trg = tid >> 4;
    const int rr = trg << 2, cc = tc << 3;

    const int arow = tid >> 2;
    const int aq4  = tid & 3;
    int gsl = m0 + arow;
    int gf = (gsl < n) ? flags[gsl] : flags[m0];
    const int fb = gf >> 13, ft = gf & (L_ - 1);
    const int we = tid >> 1;
    const int wh = tid & 1;

    float qa[4][8], ka[4][8];
#pragma unroll
    for (int i = 0; i < 4; ++i)
#pragma unroll
        for (int j = 0; j < 8; ++j) { qa[i][j] = 0.f; ka[i][j] = 0.f; }

    for (int kb = 0; kb < 32; ++kb) {
        const int k0 = kb * 32;
        {
            const float* s1 = &x[((size_t)fb * L_ + ft) * D_ + k0 + aq4 * 8];
            *(float4*)&Ats[arow][aq4 * 8]     = ((const float4*)s1)[0];
            *(float4*)&Ats[arow][aq4 * 8 + 4] = ((const float4*)s1)[1];
            const float* s2 = &x[((size_t)fb * L_ + (ft - 1)) * D_ + k0 + aq4 * 8];
            *(float4*)&Atm[arow][aq4 * 8]     = ((const float4*)s2)[0];
            *(float4*)&Atm[arow][aq4 * 8 + 4] = ((const float4*)s2)[1];
        }
        {
            const float* gq = &Wq[(size_t)(eb + we) * D_ + k0 + wh * 16];
            float tqv[16];
            *(float4*)&tqv[0]  = ((const float4*)gq)[0];
            *(float4*)&tqv[4]  = ((const float4*)gq)[1];
            *(float4*)&tqv[8]  = ((const float4*)gq)[2];
            *(float4*)&tqv[12] = ((const float4*)gq)[3];
#pragma unroll
            for (int c = 0; c < 16; ++c) wqs[wh * 16 + c][we] = tqv[c];
            const float* gk = &Wk[(size_t)(eb + we) * D_ + k0 + wh * 16];
            float tkv[16];
            *(float4*)&tkv[0]  = ((const float4*)gk)[0];
            *(float4*)&tkv[4]  = ((const float4*)gk)[1];
            *(float4*)&tkv[8]  = ((const float4*)gk)[2];
            *(float4*)&tkv[12] = ((const float4*)gk)[3];
#pragma unroll
            for (int c = 0; c < 16; ++c) wks[wh * 16 + c][we] = tkv[c];
        }
        __syncthreads();
#pragma unroll 4
        for (int k = 0; k < 32; ++k) {
            float xt[4], xm[4];
#pragma unroll
            for (int i = 0; i < 4; ++i) { xt[i] = Ats[rr + i][k]; xm[i] = Atm[rr + i][k]; }
            float wqv[8], wkv[8];
            *(float4*)&wqv[0] = *(const float4*)&wqs[k][cc];
            *(float4*)&wqv[4] = *(const float4*)&wqs[k][cc + 4];
            *(float4*)&wkv[0] = *(const float4*)&wks[k][cc];
            *(float4*)&wkv[4] = *(const float4*)&wks[k][cc + 4];
#pragma unroll
            for (int i = 0; i < 4; ++i)
#pragma unroll
                for (int j = 0; j < 8; ++j) {
                    qa[i][j] = fmaf(xt[i], wqv[j], qa[i][j]);
                    ka[i][j] = fmaf(xm[i], wkv[j], ka[i][j]);
                }
        }
        __syncthreads();
    }
#pragma unroll
    for (int i = 0; i < 4; ++i) {
        float a0 = 0.f, a1 = 0.f, a2 = 0.f;
#pragma unroll
        for (int j = 0; j < 8; ++j) {
            a0 = fmaf(qa[i][j], qa[i][j], a0);
            a1 = fmaf(ka[i][j], ka[i][j], a1);
            a2 = fmaf(qa[i][j], ka[i][j], a2);
        }
#pragma unroll
        for (int m = 1; m < 16; m <<= 1) {
            a0 += __shfl_xor(a0, m);
            a1 += __shfl_xor(a1, m);
            a2 += __shfl_xor(a2, m);
        }
        if (tc == 0 && (m0 + rr + i) < n) {
            size_t o = ((size_t)(m0 + rr + i) * 8 + blockIdx.y) * 3;
            parts[o + 0] = a0; parts[o + 1] = a1; parts[o + 2] = a2;
        }
    }
}

__global__ __launch_bounds__(256) void k_fix_final(
    const int* __restrict__ cnt, const int* __restrict__ flags,
    const float* __restrict__ parts, float* __restrict__ p)
{
    int n = *cnt; if (n > MAXF) n = MAXF;
    int f = blockIdx.x * 256 + threadIdx.x;
    if (f >= n) return;
    float a = 0.f, c = 0.f, d = 0.f;
#pragma unroll
    for (int e = 0; e < 8; ++e) {
        size_t o = ((size_t)f * 8 + e) * 3;
        a += parts[o + 0]; c += parts[o + 1]; d += parts[o + 2];
    }
    float qn = fmaxf(sqrtf(a), 1e-12f);
    float kn = fmaxf(sqrtf(c), 1e-12f);
    float cs = d / (qn * kn);
    float pv = fminf(fmaxf((1.0f - cs) * 0.5f, 0.0f), 1.0f);
    p[flags[f]] = pv;
}

// ---------------------------------------------------------------------------
// k_boundaries: compaction + per-chunk coefficient precompute.
// cw[c] = (decay, weight); segev[c] = segment end (take[c+1] or L).
// ---------------------------------------------------------------------------
__global__ __launch_bounds__(1024) void k_boundaries(
    const float* __restrict__ p, int* __restrict__ take, int* __restrict__ nch,
    float2* __restrict__ cw, int* __restrict__ segev)
{
    const int b = blockIdx.x;
    const int tid = threadIdx.x;
    __shared__ int ssum[1024];
    __shared__ int tl[C_];

    bool m[8];
    int local = 0;
#pragma unroll
    for (int j = 0; j < 8; ++j) {
        int l = tid * 8 + j;
        m[j] = (p[b * L_ + l] >= 0.5f);
        local += m[j] ? 1 : 0;
    }
    ssum[tid] = local;
    __syncthreads();
    for (int off = 1; off < 1024; off <<= 1) {
        int add = (tid >= off) ? ssum[tid - off] : 0;
        __syncthreads();
        ssum[tid] += add;
        __syncthreads();
    }
    const int total = ssum[1023];
    int rank = ssum[tid] - local;
#pragma unroll
    for (int j = 0; j < 8; ++j) {
        if (m[j]) {
            if (rank < C_) { take[b * C_ + rank] = tid * 8 + j; tl[rank] = tid * 8 + j; }
            ++rank;
        }
    }
    const int K = (total < C_) ? total : C_;
    if (tid == 0) nch[b] = K;
    for (int c = total + tid; c < C_; c += 1024) { take[b * C_ + c] = 0; tl[c] = 0; }
    __syncthreads();
    // per-chunk coefficients
    for (int c = tid; c < C_; c += 1024) {
        int idx = tl[c];
        float pc = p[b * L_ + idx];
        pc = fminf(fmaxf(pc, 1e-4f), 1.f - 1e-4f);
        float dc = (c == 0) ? 0.f : (1.f - pc);
        float wv = (c == 0) ? 1.f : pc;
        cw[b * C_ + c] = make_float2(dc, wv);
        segev[b * C_ + c] = (c + 1 < K) ? tl[c + 1] : L_;
    }
}

// ---------------------------------------------------------------------------
// k_scan_local: blocked chunk scan, 4-wide unrolled gather prefetch.
// ---------------------------------------------------------------------------
__global__ __launch_bounds__(256) void k_scan_local(
    const float* __restrict__ x, const int* __restrict__ take,
    const float2* __restrict__ cw, float* __restrict__ E, float* __restrict__ M)
{
    const int g = blockIdx.x, b = blockIdx.y, zq = blockIdx.z;
    const int d = zq * 256 + threadIdx.x;
    const int base = b * C_ + g * CG;

    float s = 0.f, mm = 1.f;
    for (int cc = 0; cc < CG; cc += 4) {
        int4 i4 = *(const int4*)&take[base + cc];
        float2 w0 = cw[base + cc], w1 = cw[base + cc + 1];
        float2 w2 = cw[base + cc + 2], w3 = cw[base + cc + 3];
        float x0 = x[((size_t)b * L_ + i4.x) * D_ + d];
        float x1 = x[((size_t)b * L_ + i4.y) * D_ + d];
        float x2 = x[((size_t)b * L_ + i4.z) * D_ + d];
        float x3 = x[((size_t)b * L_ + i4.w) * D_ + d];
        s = fmaf(w0.x, s, w0.y * x0); mm *= w0.x;
        s = fmaf(w1.x, s, w1.y * x1); mm *= w1.x;
        s = fmaf(w2.x, s, w2.y * x2); mm *= w2.x;
        s = fmaf(w3.x, s, w3.y * x3); mm *= w3.x;
    }
    E[((size_t)b * NG + g) * D_ + d] = s;
    if (threadIdx.x == 0 && zq == 0) M[b * NG + g] = mm;
}

__global__ __launch_bounds__(256) void k_scan_groups(
    const float* __restrict__ E, const float* __restrict__ M, float* __restrict__ carry)
{
    const int gid = blockIdx.x * 256 + threadIdx.x;
    const int b = gid >> 10, d = gid & 1023;
    float s = 0.f;
    for (int g = 0; g < NG; ++g) {
        carry[((size_t)b * NG + g) * D_ + d] = s;
        s = E[((size_t)b * NG + g) * D_ + d] + M[b * NG + g] * s;
    }
}

// ---------------------------------------------------------------------------
// k_scan_out: rescan + segment broadcast, EXCEPT the final capped chunk
// (its state goes to last_s; k_tail broadcasts it token-parallel).
// ---------------------------------------------------------------------------
__global__ __launch_bounds__(256) void k_scan_out(
    const float* __restrict__ x, const int* __restrict__ take,
    const float2* __restrict__ cw, const int* __restrict__ segev,
    const int* __restrict__ nch, const float* __restrict__ carry,
    float* __restrict__ last_s, float* __restrict__ out)
{
    const int g = blockIdx.x, b = blockIdx.y, zq = blockIdx.z;
    const int d = zq * 256 + threadIdx.x;
    const int K = nch[b];
    const int c0 = g * CG;
    if (c0 >= K) return;
    const int c1 = (c0 + CG < K) ? (c0 + CG) : K;
    const int base = b * C_;

    float s = carry[((size_t)b * NG + g) * D_ + d];
    int idx = take[base + c0];
    float2 w0 = cw[base + c0];
    float xv = x[((size_t)b * L_ + idx) * D_ + d];
    for (int c = c0; c < c1; ++c) {
        int idxn = 0; float2 wn = make_float2(0.f, 0.f); float xn = 0.f;
        if (c + 1 < c1) {
            idxn = take[base + c + 1];
            wn = cw[base + c + 1];
            xn = x[((size_t)b * L_ + idxn) * D_ + d];
        }
        s = fmaf(w0.x, s, w0.y * xv);
        if (c == K - 1) {
            last_s[b * D_ + d] = s;
        } else {
            int sege = segev[base + c];
            for (int l = idx; l < sege; ++l)
                out[((size_t)b * L_ + l) * D_ + d] = s;
        }
        idx = idxn; w0 = wn; xv = xn;
    }
}

// ---------------------------------------------------------------------------
// k_tail: token-parallel broadcast of the final chunk's state.
// ---------------------------------------------------------------------------
__global__ __launch_bounds__(256) void k_tail(
    const int* __restrict__ take, const int* __restrict__ nch,
    const float* __restrict__ last_s, float* __restrict__ out)
{
    const int b = blockIdx.y;
    const int tt0 = blockIdx.x * 8;
    const int K = nch[b];
    const int start = take[b * C_ + K - 1];
    if (tt0 + 8 <= start) return;
    float4 v = *(const float4*)&last_s[b * D_ + threadIdx.x * 4];
#pragma unroll
    for (int j = 0; j < 8; ++j) {
        int t = tt0 + j;
        if (t >= start)
            *(float4*)&out[((size_t)b * L_ + t) * D_ + threadIdx.x * 4] = v;
    }
}

// ---------------------------------------------------------------------------
extern "C" void kernel_launch(void* const* d_in, const int* in_sizes, int n_in,
                              void* d_out, int out_size, void* d_ws, size_t ws_size,
                              hipStream_t stream)
{
    (void)in_sizes; (void)n_in; (void)out_size;
    const float* x  = (const float*)d_in[0];
    const float* Wq = (const float*)d_in[1];
    const float* Wk = (const float*)d_in[2];
    float* out = (float*)d_out;

    char* ws = (char*)d_ws;
    float*  p      = (float*)(ws + 0);           //  131072
    int*    take   = (int*)  (ws + 131072);      //   32768
    int*    nch    = (int*)  (ws + 163840);      //     256
    float*  M      = (float*)(ws + 164096);      //     512
    float2* cw     = (float2*)(ws + 164608);     //   65536
    int*    segev  = (int*)  (ws + 230144);      //   32768
    float*  last_s = (float*)(ws + 262912);      //   16384
    int*    cnt    = (int*)  (ws + 279296);      //     256
    int*    flags  = (int*)  (ws + 279552);      //   16384
    float*  parts  = (float*)(ws + 295936);      //  393216
    float*  E      = (float*)(ws + 689152);      //  262144
    float*  carry  = (float*)(ws + 951296);      //  262144
    ushortt* eqb   = (ushortt*)(ws + 1213440);   // 2097152
    ushortt* ekb   = (ushortt*)(ws + 3310592);   // 2097152 -> 5407744 total
    if (ws_size < 5407744u) return;

    // xb lives in the (not-yet-written) output buffer: 64 MB of 128 MB.
    ushortt* xb = (ushortt*)d_out;

    hipMemsetAsync(cnt, 0, 256, stream);
    k_prep<<<dim3(512, 2), 256, 0, stream>>>(Wq, Wk, eqb, ekb);
    k_xb<<<16384, 256, 0, stream>>>(x, xb);
    k_gemm<<<dim3(64, B_), 512, 0, stream>>>(xb, eqb, ekb, x, p, cnt, flags);
    k_fix<<<dim3(MAXF / 64, 8), 256, 0, stream>>>(x, Wq, Wk, cnt, flags, parts);
    k_fix_final<<<MAXF / 256, 256, 0, stream>>>(cnt, flags, parts, p);
    k_boundaries<<<B_, 1024, 0, stream>>>(p, take, nch, cw, segev);
    dim3 g3(NG, B_, 4);
    k_scan_local<<<g3, 256, 0, stream>>>(x, take, cw, E, M);
    k_scan_groups<<<(B_ * D_) / 256, 256, 0, stream>>>(E, M, carry);
    k_scan_out<<<g3, 256, 0, stream>>>(x, take, cw, segev, nch, carry, last_s, out);
    k_tail<<<dim3(L_ / 8, B_), 256, 0, stream>>>(take, nch, last_s, out);
}